// Round 15
// baseline (1129.037 us; speedup 1.0000x reference)
//
#include <hip/hip_runtime.h>
#include <hip/hip_bf16.h>

// ---------------------------------------------------------------------------
// Fused kernel for Model_84464826843698 on gfx950 — round 15: ONE-BARRIER.
// B=4, Cin=128, N=16384, K=16, MID=64, OUT=128, SHARE=8, PT=10
// Wave-per-position: after cooperative staging (the single __syncthreads),
// wave W computes position n0+W end-to-end. All phase handoffs are
// wave-internal (wave_barrier + compiler lgkmcnt), zero cross-wave deps.
// h computed as a 32-step MFMA chain with broadcast B (no reduction).
// TP=8, 512 thr, LDS 78848 B -> 2 blocks/CU, weights streamed (no spill).
// ---------------------------------------------------------------------------

typedef __attribute__((ext_vector_type(8))) short bf16x8;
typedef __attribute__((ext_vector_type(4))) float f32x4;
typedef __attribute__((ext_vector_type(4))) unsigned short us4;

#define MFMA(a, b, c) __builtin_amdgcn_mfma_f32_16x16x32_bf16((a), (b), (c), 0, 0, 0)

// ---- LDS map (bytes) ----
#define OFF_F    0       // [8 pos][16 ks][272B] swizzled       P0 -> conv0
#define OFF_XFS  0       // [8 pos][16 k][128B rot], str 2080   overlays dead F
#define OFF_XN   34816   // [8 pos][16 ks][272B]                conv0 -> end (identity too)
#define OFF_P    69632   // [8 pos][16 ks][64B: 32 p, >=10 0]   P0 -> pt1
#define OFF_OM   77824   // [8 pos][128B: 64 mid bf16]          om -> convout
#define SMEM_BYTES 78848

// ---- d_ws element offsets (bf16) ----
#define WS_W0  0        // [128][128]
#define WS_W1  16384    // [64][128]
#define WS_W2  24576    // [64][128]
#define WS_W3  32768    // [64][128]
#define WS_P1  40960    // [64][32]  (p>=10 zero)
#define WS_P2  43008    // [64][64]
#define WS_CW1 47104    // [16][1024] permuted: [j][k*64+mid], j>=8 zero
#define WS_WO  63488    // [128][64]
#define WS_TOTAL 71680

__device__ __forceinline__ unsigned short f2b(float f) {
    union { __hip_bfloat16 h; unsigned short u; } v;
    v.h = __float2bfloat16(f);
    return v.u;
}
__device__ __forceinline__ float b2f(unsigned short u) {
    union { unsigned u; float f; } v;
    v.u = ((unsigned)u) << 16;
    return v.f;
}
__device__ __forceinline__ us4 pk4(float a, float b, float c, float d) {
    us4 r; r[0] = f2b(a); r[1] = f2b(b); r[2] = f2b(c); r[3] = f2b(d); return r;
}
__device__ __forceinline__ bf16x8 ldb(const unsigned short* p) {
    return *(const bf16x8*)p;
}

__global__ __launch_bounds__(512, 1)
void convert_weights(const float* __restrict__ w0, const float* __restrict__ w1,
                     const float* __restrict__ w2, const float* __restrict__ w3,
                     const float* __restrict__ p1, const float* __restrict__ p2,
                     const float* __restrict__ cw1, const float* __restrict__ wo,
                     unsigned short* __restrict__ ws) {
    int i = blockIdx.x * 512 + threadIdx.x;
    if (i >= WS_TOTAL) return;
    float v;
    if (i < 16384)      v = w0[i];
    else if (i < 24576) v = w1[i - 16384];
    else if (i < 32768) v = w2[i - 24576];
    else if (i < 40960) v = w3[i - 32768];
    else if (i < 43008) { int r = i - 40960, row = r >> 5, k = r & 31;
                          v = (k < 10) ? p1[row * 10 + k] : 0.f; }
    else if (i < 47104) v = p2[i - 43008];
    else if (i < 63488) { int r = i - 47104, j = r >> 10, kc = r & 1023;
                          v = (j < 8) ? cw1[j * 1024 + (kc & 63) * 16 + (kc >> 6)] : 0.f; }
    else                v = wo[i - 63488];
    ws[i] = f2b(v);
}

__global__ __launch_bounds__(512, 4)
void fused_model_kernel(const float* __restrict__ feats, const float* __restrict__ ppfs,
                        const unsigned short* __restrict__ wsb,
                        const float* __restrict__ b0, const float* __restrict__ b1,
                        const float* __restrict__ b2, const float* __restrict__ b3,
                        const float* __restrict__ cw2, const float* __restrict__ cb2,
                        const float* __restrict__ bo, float* __restrict__ out) {
    extern __shared__ char smem[];
    const int tid = threadIdx.x;
    const int W = tid >> 6;       // wave = position
    const int lane = tid & 63;
    const int kk = lane & 15;     // MFMA row/col index (= ks in C-layouts)
    const int g = lane >> 4;      // MFMA k-group
    const int bid = blockIdx.x;
    const int b = bid >> 11;
    const int n0 = (bid & 2047) * 8;

    // ---------------- P0: cooperative stage feats (swizzled) + ppfs ---------
    {
        const int kq = tid & 3, ci = tid >> 2;
        const int cisw = (ci * 2) ^ (kq << 4);
        #pragma unroll
        for (int pos = 0; pos < 8; ++pos) {
            f32x4 v = *(const f32x4*)(feats + (((size_t)b * 128 + ci) * 16384 + (n0 + pos)) * 16 + kq * 4);
            char* base = smem + OFF_F + pos * 4352 + cisw;
            *(unsigned short*)(base + (kq * 4 + 0) * 272) = f2b(v[0]);
            *(unsigned short*)(base + (kq * 4 + 1) * 272) = f2b(v[1]);
            *(unsigned short*)(base + (kq * 4 + 2) * 272) = f2b(v[2]);
            *(unsigned short*)(base + (kq * 4 + 3) * 272) = f2b(v[3]);
        }
        if (tid < 320) {                            // 8 pos x 10 p x 4 kq
            int pos = tid / 40, r = tid % 40, p = r >> 2, kq2 = r & 3;
            f32x4 v = *(const f32x4*)(ppfs + (((size_t)b * 10 + p) * 16384 + (n0 + pos)) * 16 + kq2 * 4);
            char* base = smem + OFF_P + pos * 1024 + p * 2;
            *(unsigned short*)(base + (kq2 * 4 + 0) * 64) = f2b(v[0]);
            *(unsigned short*)(base + (kq2 * 4 + 1) * 64) = f2b(v[1]);
            *(unsigned short*)(base + (kq2 * 4 + 2) * 64) = f2b(v[2]);
            *(unsigned short*)(base + (kq2 * 4 + 3) * 64) = f2b(v[3]);
        } else {                                    // zero p=10..31 (11 dwords x 128 rows)
            for (int z = tid - 320; z < 1408; z += 192) {
                int pos = z / 176, rr = z % 176, ks = rr / 11, dw = rr % 11;
                *(unsigned*)(smem + OFF_P + pos * 1024 + ks * 64 + 20 + dw * 4) = 0u;
            }
        }
    }
    __syncthreads();   // THE barrier

    // ---------------- conv0: all 8 m-tiles -> own XN slice ------------------
    {
        bf16x8 bxf[4];
        const int fsw = ((kk >> 2) & 3) << 4;
        #pragma unroll
        for (int kt = 0; kt < 4; ++kt)
            bxf[kt] = *(const bf16x8*)(smem + OFF_F + W * 4352 + kk * 272 + ((kt * 64 + 16 * g) ^ fsw));
        __builtin_amdgcn_s_setprio(1);
        #pragma unroll
        for (int mt = 0; mt < 8; ++mt) {
            f32x4 acc = {0.f, 0.f, 0.f, 0.f};
            #pragma unroll
            for (int kt = 0; kt < 4; ++kt)
                acc = MFMA(ldb(wsb + WS_W0 + (16 * mt + kk) * 128 + kt * 32 + 8 * g), bxf[kt], acc);
            f32x4 bv = *(const f32x4*)(b0 + 16 * mt + 4 * g);
            *(us4*)(smem + OFF_XN + W * 4352 + kk * 272 + (16 * mt + 4 * g) * 2) =
                pk4(fmaxf(acc[0] + bv[0], 0.f), fmaxf(acc[1] + bv[1], 0.f),
                    fmaxf(acc[2] + bv[2], 0.f), fmaxf(acc[3] + bv[3], 0.f));
        }
        __builtin_amdgcn_s_setprio(0);
    }
    __builtin_amdgcn_wave_barrier();
    __builtin_amdgcn_sched_barrier(0);

    // ---------------- pt1 -> (reg transpose) -> pt2 -> ptfpk ----------------
    us4 ptfpk[4];
    {
        bf16x8 bp = *(const bf16x8*)(smem + OFF_P + W * 1024 + kk * 64 + 16 * g);
        int pkd[4][2];
        #pragma unroll
        for (int mt = 0; mt < 4; ++mt) {
            f32x4 hv = {0.f, 0.f, 0.f, 0.f};
            hv = MFMA(ldb(wsb + WS_P1 + (16 * mt + kk) * 32 + 8 * g), bp, hv);
            us4 t = pk4(fmaxf(hv[0], 0.f), fmaxf(hv[1], 0.f), fmaxf(hv[2], 0.f), fmaxf(hv[3], 0.f));
            pkd[mt][0] = ((int*)&t)[0];
            pkd[mt][1] = ((int*)&t)[1];
        }
        const int sel = g >> 1;
        const int sa = kk + 16 * ((2 * g) & 3);
        const int sb = kk + 16 * ((2 * g + 1) & 3);
        union { int d[4]; bf16x8 v; } bh0, bh1;
        bh0.d[0] = sel ? __shfl(pkd[1][0], sa, 64) : __shfl(pkd[0][0], sa, 64);
        bh0.d[1] = sel ? __shfl(pkd[1][1], sa, 64) : __shfl(pkd[0][1], sa, 64);
        bh0.d[2] = sel ? __shfl(pkd[1][0], sb, 64) : __shfl(pkd[0][0], sb, 64);
        bh0.d[3] = sel ? __shfl(pkd[1][1], sb, 64) : __shfl(pkd[0][1], sb, 64);
        bh1.d[0] = sel ? __shfl(pkd[3][0], sa, 64) : __shfl(pkd[2][0], sa, 64);
        bh1.d[1] = sel ? __shfl(pkd[3][1], sa, 64) : __shfl(pkd[2][1], sa, 64);
        bh1.d[2] = sel ? __shfl(pkd[3][0], sb, 64) : __shfl(pkd[2][0], sb, 64);
        bh1.d[3] = sel ? __shfl(pkd[3][1], sb, 64) : __shfl(pkd[2][1], sb, 64);
        #pragma unroll
        for (int mt = 0; mt < 4; ++mt) {
            f32x4 acc = {0.f, 0.f, 0.f, 0.f};
            acc = MFMA(ldb(wsb + WS_P2 + (16 * mt + kk) * 64 + 8 * g), bh0.v, acc);
            acc = MFMA(ldb(wsb + WS_P2 + (16 * mt + kk) * 64 + 32 + 8 * g), bh1.v, acc);
            ptfpk[mt] = pk4(acc[0], acc[1], acc[2], acc[3]);
        }
    }

    // ---------------- x1 (col0 of MFMA, broadcast) + conv2 ------------------
    us4 x1pk[4], x2pk[4];
    {
        #pragma unroll
        for (int mt = 0; mt < 4; ++mt) {
            f32x4 a = {0.f, 0.f, 0.f, 0.f};
            #pragma unroll
            for (int kt = 0; kt < 4; ++kt)
                a = MFMA(ldb(wsb + WS_W1 + (16 * mt + kk) * 128 + kt * 32 + 8 * g),
                         *(const bf16x8*)(smem + OFF_XN + W * 4352 + kk * 272 + (kt * 64 + 16 * g)), a);
            f32x4 b1v = *(const f32x4*)(b1 + 16 * mt + 4 * g);
            float x0 = __shfl(a[0] + b1v[0], 16 * g, 64);   // take col ks=0 (lane kk=0 of own g)
            float x1v = __shfl(a[1] + b1v[1], 16 * g, 64);
            float x2v = __shfl(a[2] + b1v[2], 16 * g, 64);
            float x3vv = __shfl(a[3] + b1v[3], 16 * g, 64);
            x1pk[mt] = pk4(x0, x1v, x2v, x3vv);
        }
        #pragma unroll
        for (int mt = 0; mt < 4; ++mt) {
            f32x4 a = {0.f, 0.f, 0.f, 0.f};
            #pragma unroll
            for (int kt = 0; kt < 4; ++kt)
                a = MFMA(ldb(wsb + WS_W2 + (16 * mt + kk) * 128 + kt * 32 + 8 * g),
                         *(const bf16x8*)(smem + OFF_XN + W * 4352 + kk * 272 + (kt * 64 + 16 * g)), a);
            f32x4 b2v = *(const f32x4*)(b2 + 16 * mt + 4 * g);
            x2pk[mt] = pk4(a[0] + b2v[0], a[1] + b2v[1], a[2] + b2v[2], a[3] + b2v[3]);
        }
    }

    // ---------------- conv3 + combine -> x3 (regs), XFS (LDS) ---------------
    f32x4 x3v[4];
    {
        #pragma unroll
        for (int mt = 0; mt < 4; ++mt) {
            f32x4 a = {0.f, 0.f, 0.f, 0.f};
            #pragma unroll
            for (int kt = 0; kt < 4; ++kt)
                a = MFMA(ldb(wsb + WS_W3 + (16 * mt + kk) * 128 + kt * 32 + 8 * g),
                         *(const bf16x8*)(smem + OFF_XN + W * 4352 + kk * 272 + (kt * 64 + 16 * g)), a);
            f32x4 b3v = *(const f32x4*)(b3 + 16 * mt + 4 * g);
            us4 pf = ptfpk[mt], xa = x1pk[mt], xb2 = x2pk[mt];
            float p0 = b2f(pf[0]), p1v = b2f(pf[1]), p2v = b2f(pf[2]), p3 = b2f(pf[3]);
            x3v[mt][0] = a[0] + b3v[0] + p0;
            x3v[mt][1] = a[1] + b3v[1] + p1v;
            x3v[mt][2] = a[2] + b3v[2] + p2v;
            x3v[mt][3] = a[3] + b3v[3] + p3;
            *(us4*)(smem + OFF_XFS + W * 2080 + kk * 128 + ((32 * mt + 8 * g + 16 * kk) & 127)) =
                pk4(b2f(xa[0]) - b2f(xb2[0]) + p0, b2f(xa[1]) - b2f(xb2[1]) + p1v,
                    b2f(xa[2]) - b2f(xb2[2]) + p2v, b2f(xa[3]) - b2f(xb2[3]) + p3);
        }
    }
    __builtin_amdgcn_wave_barrier();
    __builtin_amdgcn_sched_barrier(0);

    // ---------------- h: 32-step MFMA chain, B broadcast over cols ----------
    float hj[8];
    {
        f32x4 hacc = {0.f, 0.f, 0.f, 0.f};
        #pragma unroll
        for (int s = 0; s < 32; ++s) {
            const int k = s >> 1;
            const int byt = (64 * (s & 1) + 16 * g + 16 * k) & 127;
            bf16x8 bf = *(const bf16x8*)(smem + OFF_XFS + W * 2080 + k * 128 + byt);
            hacc = MFMA(ldb(wsb + WS_CW1 + kk * 1024 + s * 32 + 8 * g), bf, hacc);
        }
        #pragma unroll
        for (int j = 0; j < 8; ++j)
            hj[j] = fmaxf(__shfl(hacc[j & 3], kk + 16 * (j >> 2), 64), 0.f);
    }

    // ---------------- softmax over k (in-register) --------------------------
    float w0r, w1r;
    {
        #pragma unroll
        for (int it = 0; it < 2; ++it) {
            const int c = it * 64 + lane;
            float wl = cb2[c];
            f32x4 w20 = *(const f32x4*)(cw2 + c * 8);
            f32x4 w21 = *(const f32x4*)(cw2 + c * 8 + 4);
            wl += w20[0] * hj[0] + w20[1] * hj[1] + w20[2] * hj[2] + w20[3] * hj[3];
            wl += w21[0] * hj[4] + w21[1] * hj[5] + w21[2] * hj[6] + w21[3] * hj[7];
            float mx = wl;
            for (int off = 8; off; off >>= 1) mx = fmaxf(mx, __shfl_xor(mx, off, 16));
            float e = __expf(wl - mx);
            float ss = e;
            for (int off = 8; off; off >>= 1) ss += __shfl_xor(ss, off, 16);
            if (it == 0) w0r = e / ss; else w1r = e / ss;
        }
    }

    // ---------------- om[mid] = relu(sum_k w[mid&7][k] * x3[mid][k]) --------
    {
        float wsel[4];
        #pragma unroll
        for (int r = 0; r < 4; ++r) {
            float wlo = __shfl(w0r, kk + 16 * r, 64);   // w[r][kk]
            float whi = __shfl(w1r, kk + 16 * r, 64);   // w[4+r][kk]
            wsel[r] = (g & 1) ? whi : wlo;              // j2 = 4*(g&1)+r = mid&7
        }
        float part[4][4];
        #pragma unroll
        for (int mt = 0; mt < 4; ++mt)
            #pragma unroll
            for (int r = 0; r < 4; ++r)
                part[mt][r] = x3v[mt][r] * wsel[r];
        #pragma unroll
        for (int off = 1; off < 16; off <<= 1)
            #pragma unroll
            for (int mt = 0; mt < 4; ++mt)
                #pragma unroll
                for (int r = 0; r < 4; ++r)
                    part[mt][r] += __shfl_xor(part[mt][r], off, 64);
        if (kk == 0) {
            #pragma unroll
            for (int mt = 0; mt < 4; ++mt)
                *(us4*)(smem + OFF_OM + W * 128 + (16 * mt + 4 * g) * 2) =
                    pk4(fmaxf(part[mt][0], 0.f), fmaxf(part[mt][1], 0.f),
                        fmaxf(part[mt][2], 0.f), fmaxf(part[mt][3], 0.f));
        }
    }
    __builtin_amdgcn_wave_barrier();
    __builtin_amdgcn_sched_barrier(0);

    // ---------------- convout + bias + identity -> out ----------------------
    {
        bf16x8 bom0 = *(const bf16x8*)(smem + OFF_OM + W * 128 + (8 * g) * 2);
        bf16x8 bom1 = *(const bf16x8*)(smem + OFF_OM + W * 128 + (32 + 8 * g) * 2);
        #pragma unroll
        for (int mt = 0; mt < 8; ++mt) {
            f32x4 acc = {0.f, 0.f, 0.f, 0.f};
            acc = MFMA(ldb(wsb + WS_WO + (16 * mt + kk) * 64 + 8 * g), bom0, acc);
            acc = MFMA(ldb(wsb + WS_WO + (16 * mt + kk) * 64 + 32 + 8 * g), bom1, acc);
            if (kk == 0) {
                f32x4 bv = *(const f32x4*)(bo + 16 * mt + 4 * g);
                us4 xcv = *(const us4*)(smem + OFF_XN + W * 4352 + (16 * mt + 4 * g) * 2);  // ks=0 row
                #pragma unroll
                for (int r = 0; r < 4; ++r) {
                    int o = 16 * mt + 4 * g + r;
                    out[((size_t)b * 128 + o) * 16384 + n0 + W] = acc[r] + bv[r] + b2f(xcv[r]);
                }
            }
        }
    }
}

extern "C" void kernel_launch(void* const* d_in, const int* in_sizes, int n_in,
                              void* d_out, int out_size, void* d_ws, size_t ws_size,
                              hipStream_t stream) {
    (void)in_sizes; (void)n_in; (void)out_size; (void)ws_size;
    const float* feats = (const float*)d_in[0];
    const float* ppfs  = (const float*)d_in[1];
    const float* w0  = (const float*)d_in[2];
    const float* b0  = (const float*)d_in[3];
    const float* w1  = (const float*)d_in[4];
    const float* b1  = (const float*)d_in[5];
    const float* w2  = (const float*)d_in[6];
    const float* b2  = (const float*)d_in[7];
    const float* w3  = (const float*)d_in[8];
    const float* b3  = (const float*)d_in[9];
    const float* cw1 = (const float*)d_in[10];
    const float* cw2 = (const float*)d_in[11];
    const float* cb2 = (const float*)d_in[12];
    const float* wo  = (const float*)d_in[13];
    const float* bo  = (const float*)d_in[14];
    const float* p1  = (const float*)d_in[15];
    const float* p2  = (const float*)d_in[16];
    float* out = (float*)d_out;
    unsigned short* wsb = (unsigned short*)d_ws;

    convert_weights<<<dim3((WS_TOTAL + 511) / 512), dim3(512), 0, stream>>>(
        w0, w1, w2, w3, p1, p2, cw1, wo, wsb);

    fused_model_kernel<<<dim3(8192), dim3(512), SMEM_BYTES, stream>>>(
        feats, ppfs, wsb, b0, b1, b2, b3, cw2, cb2, bo, out);
}

// Round 16
// 300.896 us; speedup vs baseline: 3.7522x; 3.7522x over previous
//
#include <hip/hip_runtime.h>
#include <hip/hip_bf16.h>

// ---------------------------------------------------------------------------
// Fused kernel for Model_84464826843698 on gfx950 — FINAL (r9/r14 restoration).
// B=4, Cin=128, N=16384, K=16, MID=64, OUT=128, SHARE=8, PT=10
// Best verified: 301.3 us (reproduced twice). Single-tile TP=8, 512 thr
// (8 waves), LDS 81088 B, 2 blocks/CU, 6 barriers. Weights pre-converted to
// bf16 (d_ws); phase-early L2 fragment issue; s_setprio around MFMA clusters;
// swizzled F staging; rotated XFS; LDS-atomic h-reduction; wave-local
// softmax/K-sum. Measured dead ends: occupancy pushes (r2/r8), multi-tile
// pipelining (r7/r11/r12/r13: spill xor 1 blk/CU), wave-per-position (r15:
// loses weight reuse, 3.7x worse).
// ---------------------------------------------------------------------------

typedef __attribute__((ext_vector_type(8))) short bf16x8;
typedef __attribute__((ext_vector_type(4))) float f32x4;
typedef __attribute__((ext_vector_type(4))) unsigned short us4;

#define MFMA(a, b, c) __builtin_amdgcn_mfma_f32_16x16x32_bf16((a), (b), (c), 0, 0, 0)

// ---- LDS map (bytes) ----
#define OFF_F    0       // [8 pos][16 ks][272B], ch-byte ^= ((ks>>2)&3)<<4   P0->P1
#define OFF_X2   0       // [8 pos][16 ks][136B]                              P2->P4
#define OFF_PTF  17408   // [8 pos][16 ks][136B]                              P2->P4
#define OFF_XN   34816   // [8 pos][16 ks][272B] linear                       P1->P3
#define OFF_X3   34816   // [8 pos][16 ks][136B]                              P4->P7
#define OFF_XFS  52224   // [8 pos][16 k][128B], row rotated 16*k B, str 2080 P4->P5
#define OFF_P    69632   // [8 pos][16 ks][64B: 32 p bf16, p>=10 zero]        P0->P2
#define OFF_WS   69632   // [8 pos][8 j2][80B: 16 k f32 + pad]                P6->P7
#define OFF_HB   74752   // [8 pos][8 j] f32 (atomicAdd target)               P4->P6
#define OFF_OM   76288   // [8 pos][144B: 64 mid bf16 + pad]                  P7->P8
#define OFF_X1   77824   // [8 pos][136B]                                     P2->P4
#define OFF_XC   78912   // [8 pos][272B] identity                            P1->P8
#define SMEM_BYTES 81088

// ---- d_ws element offsets (bf16) ----
#define WS_W0  0        // [128][128]
#define WS_W1  16384    // [64][128]
#define WS_W2  24576    // [64][128]
#define WS_W3  32768    // [64][128]
#define WS_P1  40960    // [64][32]  (p>=10 zero)
#define WS_P2  43008    // [64][64]
#define WS_CW1 47104    // [16][1024] permuted: [j][k*64+mid], j>=8 zero
#define WS_WO  63488    // [128][64]
#define WS_TOTAL 71680

__device__ __forceinline__ unsigned short f2b(float f) {
    union { __hip_bfloat16 h; unsigned short u; } v;
    v.h = __float2bfloat16(f);
    return v.u;
}
__device__ __forceinline__ float b2f(unsigned short u) {
    union { unsigned u; float f; } v;
    v.u = ((unsigned)u) << 16;
    return v.f;
}
__device__ __forceinline__ us4 pk4(float a, float b, float c, float d) {
    us4 r; r[0] = f2b(a); r[1] = f2b(b); r[2] = f2b(c); r[3] = f2b(d); return r;
}
__device__ __forceinline__ bf16x8 ldb(const unsigned short* p) {
    return *(const bf16x8*)p;
}

__global__ __launch_bounds__(512, 1)
void convert_weights(const float* __restrict__ w0, const float* __restrict__ w1,
                     const float* __restrict__ w2, const float* __restrict__ w3,
                     const float* __restrict__ p1, const float* __restrict__ p2,
                     const float* __restrict__ cw1, const float* __restrict__ wo,
                     unsigned short* __restrict__ ws) {
    int i = blockIdx.x * 512 + threadIdx.x;
    if (i >= WS_TOTAL) return;
    float v;
    if (i < 16384)      v = w0[i];
    else if (i < 24576) v = w1[i - 16384];
    else if (i < 32768) v = w2[i - 24576];
    else if (i < 40960) v = w3[i - 32768];
    else if (i < 43008) { int r = i - 40960, row = r >> 5, k = r & 31;
                          v = (k < 10) ? p1[row * 10 + k] : 0.f; }
    else if (i < 47104) v = p2[i - 43008];
    else if (i < 63488) { int r = i - 47104, j = r >> 10, kc = r & 1023;
                          v = (j < 8) ? cw1[j * 1024 + (kc & 63) * 16 + (kc >> 6)] : 0.f; }
    else                v = wo[i - 63488];
    ws[i] = f2b(v);
}

__global__ __launch_bounds__(512, 4)
void fused_model_kernel(const float* __restrict__ feats, const float* __restrict__ ppfs,
                        const unsigned short* __restrict__ wsb,
                        const float* __restrict__ b0, const float* __restrict__ b1,
                        const float* __restrict__ b2, const float* __restrict__ b3,
                        const float* __restrict__ cw2, const float* __restrict__ cb2,
                        const float* __restrict__ bo, float* __restrict__ out) {
    extern __shared__ char smem[];
    const int tid = threadIdx.x;
    const int W = tid >> 6;
    const int lane = tid & 63;
    const int kk = lane & 15;     // MFMA row/col index
    const int g = lane >> 4;      // MFMA k-group
    const int bid = blockIdx.x;
    const int b = bid >> 11;
    const int n0 = (bid & 2047) * 8;

    // ---------------- Prologue: prefetch phase-1/2 weight A-fragments -------
    bf16x8 a0[4], rA[4], rB[4];
    {
        const int mtr = (W & 3);
        #pragma unroll
        for (int kt = 0; kt < 4; ++kt) {
            a0[kt] = ldb(wsb + WS_W0 + (16 * W + kk) * 128 + kt * 32 + 8 * g);
            if (W < 4) {
                rA[kt] = ldb(wsb + WS_W3 + (16 * mtr + kk) * 128 + kt * 32 + 8 * g);  // conv3
                rB[kt] = ldb(wsb + WS_W1 + (16 * mtr + kk) * 128 + kt * 32 + 8 * g);  // x1
            } else {
                rA[kt] = ldb(wsb + WS_W2 + (16 * mtr + kk) * 128 + kt * 32 + 8 * g);  // conv2
                rB[kt] = ldb(wsb + WS_W3 + (16 * mtr + kk) * 128 + kt * 32 + 8 * g);  // conv3
            }
        }
    }

    // ---------------- P0: stage feats (fp32->bf16, swizzled) + ppfs ---------
    {
        const int kq = tid & 3, ci = tid >> 2;
        const int cisw = (ci * 2) ^ (kq << 4);
        #pragma unroll
        for (int pos = 0; pos < 8; ++pos) {
            f32x4 v = *(const f32x4*)(feats + (((size_t)b * 128 + ci) * 16384 + (n0 + pos)) * 16 + kq * 4);
            char* base = smem + OFF_F + pos * 4352 + cisw;
            *(unsigned short*)(base + (kq * 4 + 0) * 272) = f2b(v[0]);
            *(unsigned short*)(base + (kq * 4 + 1) * 272) = f2b(v[1]);
            *(unsigned short*)(base + (kq * 4 + 2) * 272) = f2b(v[2]);
            *(unsigned short*)(base + (kq * 4 + 3) * 272) = f2b(v[3]);
        }
        if (tid < 320) {                            // 8 pos x 10 p x 4 kq
            int pos = tid / 40, r = tid % 40, p = r >> 2, kq2 = r & 3;
            f32x4 v = *(const f32x4*)(ppfs + (((size_t)b * 10 + p) * 16384 + (n0 + pos)) * 16 + kq2 * 4);
            char* base = smem + OFF_P + pos * 1024 + p * 2;
            *(unsigned short*)(base + (kq2 * 4 + 0) * 64) = f2b(v[0]);
            *(unsigned short*)(base + (kq2 * 4 + 1) * 64) = f2b(v[1]);
            *(unsigned short*)(base + (kq2 * 4 + 2) * 64) = f2b(v[2]);
            *(unsigned short*)(base + (kq2 * 4 + 3) * 64) = f2b(v[3]);
        } else {                                    // zero p=10..31 (11 dwords x 128 rows)
            for (int z = tid - 320; z < 1408; z += 192) {
                int pos = z / 176, rr = z % 176, ks = rr / 11, dw = rr % 11;
                *(unsigned*)(smem + OFF_P + pos * 1024 + ks * 64 + 20 + dw * 4) = 0u;
            }
        }
    }
    __syncthreads();   // B0

    // ---------------- P1: conv0 -> relu -> XN (+ identity XC) ---------------
    {
        f32x4 bv = *(const f32x4*)(b0 + 16 * W + 4 * g);
        const int fsw = ((kk >> 2) & 3) << 4;
        __builtin_amdgcn_s_setprio(1);
        #pragma unroll
        for (int pos = 0; pos < 8; ++pos) {
            f32x4 acc = {0.f, 0.f, 0.f, 0.f};
            #pragma unroll
            for (int kt = 0; kt < 4; ++kt) {
                bf16x8 bf = *(const bf16x8*)(smem + OFF_F + pos * 4352 + kk * 272 + ((kt * 64 + 16 * g) ^ fsw));
                acc = MFMA(a0[kt], bf, acc);
            }
            us4 xw = pk4(fmaxf(acc[0] + bv[0], 0.f), fmaxf(acc[1] + bv[1], 0.f),
                         fmaxf(acc[2] + bv[2], 0.f), fmaxf(acc[3] + bv[3], 0.f));
            *(us4*)(smem + OFF_XN + pos * 4352 + kk * 272 + (16 * W + 4 * g) * 2) = xw;
            if (kk == 0) *(us4*)(smem + OFF_XC + pos * 272 + (16 * W + 4 * g) * 2) = xw;
        }
        __builtin_amdgcn_s_setprio(0);
    }
    // issue P2's pt weight fragments NOW (vmcnt survives the barrier; latency
    // hides under other waves' P1 + barrier drain)
    bf16x8 a1f[4], a2f0[4], a2f1[4];
    if (W < 4) {
        #pragma unroll
        for (int mt = 0; mt < 4; ++mt) {
            a1f[mt]  = ldb(wsb + WS_P1 + (16 * mt + kk) * 32 + 8 * g);
            a2f0[mt] = ldb(wsb + WS_P2 + (16 * mt + kk) * 64 + 8 * g);
            a2f1[mt] = ldb(wsb + WS_P2 + (16 * mt + kk) * 64 + 32 + 8 * g);
        }
    }
    __syncthreads();   // B1

    // ---------------- P2: pt+conv3(0-3)+x1 (w0-3) | conv2+conv3(4-7) (w4-7) -
    f32x4 acc3[4];   // conv3 accumulators; mapping = (mt = W&3, ph = W>>2)
    if (W < 4) {
        const int sel = g >> 1;
        const int sa = kk + 16 * ((2 * g) & 3);
        const int sb = kk + 16 * ((2 * g + 1) & 3);
        __builtin_amdgcn_s_setprio(1);
        #pragma unroll
        for (int pp2 = 0; pp2 < 2; ++pp2) {
            const int pos = 2 * W + pp2;
            bf16x8 bp = *(const bf16x8*)(smem + OFF_P + pos * 1024 + kk * 64 + 16 * g);
            int pkd[4][2];
            #pragma unroll
            for (int mt = 0; mt < 4; ++mt) {
                f32x4 hv = {0.f, 0.f, 0.f, 0.f};
                hv = MFMA(a1f[mt], bp, hv);
                us4 t = pk4(fmaxf(hv[0], 0.f), fmaxf(hv[1], 0.f),
                            fmaxf(hv[2], 0.f), fmaxf(hv[3], 0.f));
                pkd[mt][0] = ((int*)&t)[0];
                pkd[mt][1] = ((int*)&t)[1];
            }
            union { int d[4]; bf16x8 v; } bh0, bh1;
            bh0.d[0] = sel ? __shfl(pkd[1][0], sa, 64) : __shfl(pkd[0][0], sa, 64);
            bh0.d[1] = sel ? __shfl(pkd[1][1], sa, 64) : __shfl(pkd[0][1], sa, 64);
            bh0.d[2] = sel ? __shfl(pkd[1][0], sb, 64) : __shfl(pkd[0][0], sb, 64);
            bh0.d[3] = sel ? __shfl(pkd[1][1], sb, 64) : __shfl(pkd[0][1], sb, 64);
            bh1.d[0] = sel ? __shfl(pkd[3][0], sa, 64) : __shfl(pkd[2][0], sa, 64);
            bh1.d[1] = sel ? __shfl(pkd[3][1], sa, 64) : __shfl(pkd[2][1], sa, 64);
            bh1.d[2] = sel ? __shfl(pkd[3][0], sb, 64) : __shfl(pkd[2][0], sb, 64);
            bh1.d[3] = sel ? __shfl(pkd[3][1], sb, 64) : __shfl(pkd[2][1], sb, 64);
            #pragma unroll
            for (int mt = 0; mt < 4; ++mt) {
                f32x4 acc = {0.f, 0.f, 0.f, 0.f};
                acc = MFMA(a2f0[mt], bh0.v, acc);
                acc = MFMA(a2f1[mt], bh1.v, acc);
                *(us4*)(smem + OFF_PTF + pos * 2176 + kk * 136 + (16 * mt + 4 * g) * 2) =
                    pk4(acc[0], acc[1], acc[2], acc[3]);
            }
        }
        #pragma unroll
        for (int pp2 = 0; pp2 < 4; ++pp2) {
            f32x4 acc = {0.f, 0.f, 0.f, 0.f};
            #pragma unroll
            for (int kt = 0; kt < 4; ++kt) {
                bf16x8 bf = *(const bf16x8*)(smem + OFF_XN + pp2 * 4352 + kk * 272 + (kt * 64 + 16 * g));
                acc = MFMA(rA[kt], bf, acc);
            }
            acc3[pp2] = acc;
        }
        f32x4 a1c = {0.f, 0.f, 0.f, 0.f};
        #pragma unroll
        for (int kt = 0; kt < 4; ++kt) {
            bf16x8 bf = *(const bf16x8*)(smem + OFF_XC + (kk & 7) * 272 + (kt * 64 + 16 * g));
            a1c = MFMA(rB[kt], bf, a1c);
        }
        __builtin_amdgcn_s_setprio(0);
        if (kk < 8) {
            f32x4 b1v = *(const f32x4*)(b1 + 16 * W + 4 * g);
            *(us4*)(smem + OFF_X1 + kk * 136 + (16 * W + 4 * g) * 2) =
                pk4(a1c[0] + b1v[0], a1c[1] + b1v[1], a1c[2] + b1v[2], a1c[3] + b1v[3]);
        }
    } else {
        const int mt = W - 4;
        f32x4 b2v = *(const f32x4*)(b2 + 16 * mt + 4 * g);
        __builtin_amdgcn_s_setprio(1);
        #pragma unroll
        for (int pos = 0; pos < 8; ++pos) {
            bf16x8 bx[4];
            #pragma unroll
            for (int kt = 0; kt < 4; ++kt)
                bx[kt] = *(const bf16x8*)(smem + OFF_XN + pos * 4352 + kk * 272 + (kt * 64 + 16 * g));
            f32x4 acc = {0.f, 0.f, 0.f, 0.f};
            #pragma unroll
            for (int kt = 0; kt < 4; ++kt) acc = MFMA(rA[kt], bx[kt], acc);
            *(us4*)(smem + OFF_X2 + pos * 2176 + kk * 136 + (16 * mt + 4 * g) * 2) =
                pk4(acc[0] + b2v[0], acc[1] + b2v[1], acc[2] + b2v[2], acc[3] + b2v[3]);
            if (pos >= 4) {      // conv3 for pos 4..7 shares bx
                f32x4 c = {0.f, 0.f, 0.f, 0.f};
                #pragma unroll
                for (int kt = 0; kt < 4; ++kt) c = MFMA(rB[kt], bx[kt], c);
                acc3[pos - 4] = c;
            }
        }
        __builtin_amdgcn_s_setprio(0);
    }
    __syncthreads();   // B2

    // ---------------- P4: combine -> X3, XFS (+ HB zero) --------------------
    {
        const int mt = W & 3, ph = W >> 2;
        f32x4 b3v = *(const f32x4*)(b3 + 16 * mt + 4 * g);
        const int rot = (32 * mt + 8 * g + 16 * kk) & 127;
        #pragma unroll
        for (int pp2 = 0; pp2 < 4; ++pp2) {
            const int pos = ph * 4 + pp2;
            us4 ptfv = *(const us4*)(smem + OFF_PTF + pos * 2176 + kk * 136 + (16 * mt + 4 * g) * 2);
            us4 x2v  = *(const us4*)(smem + OFF_X2  + pos * 2176 + kk * 136 + (16 * mt + 4 * g) * 2);
            us4 x1v  = *(const us4*)(smem + OFF_X1  + pos * 136 + (16 * mt + 4 * g) * 2);
            float pf0 = b2f(ptfv[0]), pf1 = b2f(ptfv[1]), pf2 = b2f(ptfv[2]), pf3 = b2f(ptfv[3]);
            *(us4*)(smem + OFF_X3 + pos * 2176 + kk * 136 + (16 * mt + 4 * g) * 2) =
                pk4(acc3[pp2][0] + b3v[0] + pf0, acc3[pp2][1] + b3v[1] + pf1,
                    acc3[pp2][2] + b3v[2] + pf2, acc3[pp2][3] + b3v[3] + pf3);
            *(us4*)(smem + OFF_XFS + pos * 2080 + kk * 128 + rot) =
                pk4(b2f(x1v[0]) - b2f(x2v[0]) + pf0, b2f(x1v[1]) - b2f(x2v[1]) + pf1,
                    b2f(x1v[2]) - b2f(x2v[2]) + pf2, b2f(x1v[3]) - b2f(x2v[3]) + pf3);
        }
        if (tid < 64) *(float*)(smem + OFF_HB + tid * 4) = 0.f;
    }
    // issue P5's cw1 fragments before the barrier (latency hidden by drain)
    bf16x8 acw[4];
    {
        #pragma unroll
        for (int kt = 0; kt < 4; ++kt)
            acw[kt] = ldb(wsb + WS_CW1 + kk * 1024 + W * 128 + kt * 32 + 8 * g);
    }
    __syncthreads();   // B3

    // ---------------- P5: h partials via MFMA -> LDS atomicAdd --------------
    {
        const char* xb = smem + OFF_XFS + (kk & 7) * 2080;
        f32x4 acc = {0.f, 0.f, 0.f, 0.f};
        #pragma unroll
        for (int kt = 0; kt < 4; ++kt) {
            const int k = 2 * W + (kt >> 1);
            const int byt = (64 * (kt & 1) + 16 * g + 16 * k) & 127;
            bf16x8 bf = *(const bf16x8*)(xb + k * 128 + byt);
            acc = MFMA(acw[kt], bf, acc);
        }
        if (kk < 8 && g < 2) {
            #pragma unroll
            for (int r = 0; r < 4; ++r)
                atomicAdd((float*)(smem + OFF_HB + kk * 32 + (4 * g + r) * 4), acc[r]);
        }
    }
    __syncthreads();   // B4

    // ---------------- P6+P7: wave-local (pos = W) ---------------------------
    bf16x8 woF[2];     // P8's wo fragments — issue early, used after B5
    woF[0] = ldb(wsb + WS_WO + (16 * W + kk) * 64 + 8 * g);
    woF[1] = ldb(wsb + WS_WO + (16 * W + kk) * 64 + 32 + 8 * g);
    {
        const int pos = W;
        f32x4 h0 = *(const f32x4*)(smem + OFF_HB + pos * 32);
        f32x4 h1 = *(const f32x4*)(smem + OFF_HB + pos * 32 + 16);
        #pragma unroll
        for (int r = 0; r < 4; ++r) { h0[r] = fmaxf(h0[r], 0.f); h1[r] = fmaxf(h1[r], 0.f); }
        #pragma unroll
        for (int it = 0; it < 2; ++it) {
            const int c = it * 64 + lane;
            float wl = cb2[c];
            f32x4 w20 = *(const f32x4*)(cw2 + c * 8);
            f32x4 w21 = *(const f32x4*)(cw2 + c * 8 + 4);
            #pragma unroll
            for (int j = 0; j < 4; ++j) {
                wl += w20[j] * h0[j];
                wl += w21[j] * h1[j];
            }
            float mx = wl;
            for (int off = 8; off; off >>= 1) mx = fmaxf(mx, __shfl_xor(mx, off, 16));
            float e = __expf(wl - mx);
            float ss = e;
            for (int off = 8; off; off >>= 1) ss += __shfl_xor(ss, off, 16);
            *(float*)(smem + OFF_WS + pos * 640 + (4 * it + g) * 80 + kk * 4) = e / ss;
        }
        __builtin_amdgcn_wave_barrier();
        __builtin_amdgcn_sched_barrier(0);

        const char* wsp = smem + OFF_WS + pos * 640 + (lane & 7) * 80;
        f32x4 wv0 = *(const f32x4*)(wsp);
        f32x4 wv1 = *(const f32x4*)(wsp + 16);
        f32x4 wv2 = *(const f32x4*)(wsp + 32);
        f32x4 wv3 = *(const f32x4*)(wsp + 48);
        const char* x3b = smem + OFF_X3 + pos * 2176 + lane * 2;
        float s = 0.f;
        #pragma unroll
        for (int k = 0; k < 4; ++k) s += wv0[k] * b2f(*(const unsigned short*)(x3b + k * 136));
        #pragma unroll
        for (int k = 0; k < 4; ++k) s += wv1[k] * b2f(*(const unsigned short*)(x3b + (k + 4) * 136));
        #pragma unroll
        for (int k = 0; k < 4; ++k) s += wv2[k] * b2f(*(const unsigned short*)(x3b + (k + 8) * 136));
        #pragma unroll
        for (int k = 0; k < 4; ++k) s += wv3[k] * b2f(*(const unsigned short*)(x3b + (k + 12) * 136));
        *(unsigned short*)(smem + OFF_OM + pos * 144 + lane * 2) = f2b(fmaxf(s, 0.f));
    }
    __syncthreads();   // B5

    // ---------------- P8: convout + bias + identity -> out ------------------
    {
        f32x4 acc = {0.f, 0.f, 0.f, 0.f};
        #pragma unroll
        for (int kt = 0; kt < 2; ++kt) {
            bf16x8 bf = *(const bf16x8*)(smem + OFF_OM + (kk & 7) * 144 + (kt * 64 + 16 * g));
            acc = MFMA(woF[kt], bf, acc);
        }
        if (kk < 8) {
            f32x4 bv = *(const f32x4*)(bo + 16 * W + 4 * g);
            us4 xcv = *(const us4*)(smem + OFF_XC + kk * 272 + (16 * W + 4 * g) * 2);
            #pragma unroll
            for (int r = 0; r < 4; ++r) {
                int o = 16 * W + 4 * g + r;
                out[((size_t)b * 128 + o) * 16384 + n0 + kk] = acc[r] + bv[r] + b2f(xcv[r]);
            }
        }
    }
}

extern "C" void kernel_launch(void* const* d_in, const int* in_sizes, int n_in,
                              void* d_out, int out_size, void* d_ws, size_t ws_size,
                              hipStream_t stream) {
    (void)in_sizes; (void)n_in; (void)out_size; (void)ws_size;
    const float* feats = (const float*)d_in[0];
    const float* ppfs  = (const float*)d_in[1];
    const float* w0  = (const float*)d_in[2];
    const float* b0  = (const float*)d_in[3];
    const float* w1  = (const float*)d_in[4];
    const float* b1  = (const float*)d_in[5];
    const float* w2  = (const float*)d_in[6];
    const float* b2  = (const float*)d_in[7];
    const float* w3  = (const float*)d_in[8];
    const float* b3  = (const float*)d_in[9];
    const float* cw1 = (const float*)d_in[10];
    const float* cw2 = (const float*)d_in[11];
    const float* cb2 = (const float*)d_in[12];
    const float* wo  = (const float*)d_in[13];
    const float* bo  = (const float*)d_in[14];
    const float* p1  = (const float*)d_in[15];
    const float* p2  = (const float*)d_in[16];
    float* out = (float*)d_out;
    unsigned short* wsb = (unsigned short*)d_ws;

    convert_weights<<<dim3((WS_TOTAL + 511) / 512), dim3(512), 0, stream>>>(
        w0, w1, w2, w3, p1, p2, cw1, wo, wsb);

    (void)hipFuncSetAttribute(reinterpret_cast<const void*>(fused_model_kernel),
                              hipFuncAttributeMaxDynamicSharedMemorySize, SMEM_BYTES);
    fused_model_kernel<<<dim3(8192), dim3(512), SMEM_BYTES, stream>>>(
        feats, ppfs, wsb, b0, b1, b2, b3, cw2, cb2, bo, out);
}